// Round 3
// baseline (168.124 us; speedup 1.0000x reference)
//
#include <hip/hip_runtime.h>

// LengthRegulator: out[b,pos,:] = x[b, src(b,pos), :] masked by pos < total[b]
// B=16, T=1024, D=512, MAXLEN=4096 (fixed by setup_inputs()).

#define BB 16
#define TT 1024
#define DD 512
#define MAXLEN 4096

typedef float v4f __attribute__((ext_vector_type(4)));  // native vector: OK for
                                                        // __builtin_nontemporal_*

// ---------------------------------------------------------------------------
// Kernel 1: per-batch clamp + inclusive scan of 1024 durations, scatter the
// inverse map. One block of 1024 threads per batch (one thread per t).
// srcTab[b*MAXLEN + pos] = t with csum[t-1] <= pos < csum[t], or -1 in tail.
// ---------------------------------------------------------------------------
__global__ __launch_bounds__(1024) void build_src_kernel(
    const int* __restrict__ dur, int* __restrict__ srcTab) {
  const int b = blockIdx.x;
  const int tid = threadIdx.x;
  const int lane = tid & 63;
  const int wid = tid >> 6;  // 16 waves

  const int d = max(dur[b * TT + tid], 0);

  // inclusive wave scan via shuffles
  int v = d;
#pragma unroll
  for (int off = 1; off < 64; off <<= 1) {
    int n = __shfl_up(v, off, 64);
    if (lane >= off) v += n;
  }

  __shared__ int wsum[16];
  __shared__ int s_total;
  if (lane == 63) wsum[wid] = v;
  __syncthreads();

  // add sums of preceding waves (<=15 broadcast LDS reads)
  int add = 0;
  for (int i = 0; i < wid; ++i) add += wsum[i];
  const int incl = v + add;
  const int excl = incl - d;

  if (tid == TT - 1) s_total = incl;
  __syncthreads();
  const int total = s_total;

  int* st = srcTab + b * MAXLEN;
  for (int p = excl; p < incl; ++p) st[p] = tid;   // run of length d
  for (int p = total + tid; p < MAXLEN; p += 1024) st[p] = -1;  // masked tail
}

// ---------------------------------------------------------------------------
// Kernel 2: gather. 4 waves/block, each wave copies 4 consecutive output rows
// (512 floats = 128 float4 each; lane i handles float4 i and i+64).
// All 4 srcTab loads then all 8 x-loads issued before any store (MLP).
// Output is streamed with nontemporal stores (no reuse; keep L2 for x).
// ---------------------------------------------------------------------------
__global__ __launch_bounds__(256) void gather_kernel(
    const v4f* __restrict__ x, const int* __restrict__ srcTab,
    v4f* __restrict__ out) {
  const int gw = (int)(blockIdx.x * 4u + (threadIdx.x >> 6));
  const int lane = threadIdx.x & 63;
  const int base = gw * 4;       // first of 4 rows; groups never cross batch
  const int b = base >> 12;      // row / MAXLEN

  int s[4];
#pragma unroll
  for (int i = 0; i < 4; ++i) s[i] = srcTab[base + i];

  v4f v0[4], v1[4];
  const v4f* xb = x + (size_t)b * TT * (DD / 4);
#pragma unroll
  for (int i = 0; i < 4; ++i) {
    const int src = (s[i] < 0) ? 0 : s[i];  // safe load even when masked
    const v4f* ip = xb + (size_t)src * (DD / 4);
    v0[i] = ip[lane];
    v1[i] = ip[lane + 64];
  }

  const v4f z = {0.f, 0.f, 0.f, 0.f};
#pragma unroll
  for (int i = 0; i < 4; ++i) {
    if (s[i] < 0) { v0[i] = z; v1[i] = z; }
    v4f* op = out + (size_t)(base + i) * (DD / 4);
    __builtin_nontemporal_store(v0[i], op + lane);
    __builtin_nontemporal_store(v1[i], op + lane + 64);
  }
}

extern "C" void kernel_launch(void* const* d_in, const int* in_sizes, int n_in,
                              void* d_out, int out_size, void* d_ws,
                              size_t ws_size, hipStream_t stream) {
  const float* x = (const float*)d_in[0];
  const int* dur = (const int*)d_in[1];
  int* srcTab = (int*)d_ws;  // BB*MAXLEN ints = 256 KiB

  build_src_kernel<<<BB, 1024, 0, stream>>>(dur, srcTab);

  const int rows = BB * MAXLEN;  // 65536 rows, 16 rows per block
  gather_kernel<<<rows / 16, 256, 0, stream>>>((const v4f*)x, srcTab,
                                               (v4f*)d_out);
}

// Round 4
// 165.455 us; speedup vs baseline: 1.0161x; 1.0161x over previous
//
#include <hip/hip_runtime.h>

// LengthRegulator: out[b,pos,:] = x[b, src(b,pos), :] masked by pos < total[b]
// B=16, T=1024, D=512, MAXLEN=4096 (fixed by setup_inputs()).
//
// Single fused kernel. Each block of 256 threads handles 16 consecutive
// output rows of one batch:
//   1. cooperative clamp+scan of the batch's 1024 durations (4/thread local
//      scan + wave shuffle scan + 4-wave LDS combine) -> csum[1024] in LDS
//   2. 16 threads binary-search their block's 16 positions -> s_src[16]
//   3. wave-per-row copy: lane i moves float4 i and i+64 (fully coalesced),
//      nontemporal stores (output is write-once, keep L2/L3 for x).
// The redundant per-block scan reads 4 KB of durations (L2-hit after first
// touch per batch) and costs ~1-2 us latency, hidden by ~16 blocks/CU.

#define BB 16
#define TT 1024
#define DD 512
#define MAXLEN 4096

typedef float v4f __attribute__((ext_vector_type(4)));
typedef int v4i __attribute__((ext_vector_type(4)));

__global__ __launch_bounds__(256) void lr_fused_kernel(
    const v4f* __restrict__ x, const int* __restrict__ dur,
    v4f* __restrict__ out) {
  const int blk = blockIdx.x;          // 4096 blocks
  const int b = blk >> 8;              // 256 blocks per batch
  const int rbase = (blk & 255) << 4;  // first of this block's 16 rows
  const int tid = threadIdx.x;
  const int lane = tid & 63;
  const int wid = tid >> 6;            // 4 waves

  __shared__ int csum[TT];   // inclusive cumsum of clamped durations
  __shared__ int wsum[4];
  __shared__ int s_src[16];

  // ---- 1. scan ----
  const v4i dd = ((const v4i*)(dur + b * TT))[tid];  // 4 durations/thread
  const int d0 = max(dd.x, 0), d1 = max(dd.y, 0);
  const int d2 = max(dd.z, 0), d3 = max(dd.w, 0);
  const int l0 = d0, l1 = l0 + d1, l2 = l1 + d2, l3 = l2 + d3;

  int v = l3;  // inclusive wave scan of per-thread chunk sums
#pragma unroll
  for (int off = 1; off < 64; off <<= 1) {
    const int n = __shfl_up(v, off, 64);
    if (lane >= off) v += n;
  }
  if (lane == 63) wsum[wid] = v;
  __syncthreads();

  int add = 0;
  for (int i = 0; i < wid; ++i) add += wsum[i];
  const int total = wsum[0] + wsum[1] + wsum[2] + wsum[3];
  const int excl = add + v - l3;  // exclusive prefix before this chunk
  const int t4 = tid << 2;
  csum[t4 + 0] = excl + l0;
  csum[t4 + 1] = excl + l1;
  csum[t4 + 2] = excl + l2;
  csum[t4 + 3] = excl + l3;
  __syncthreads();

  // ---- 2. searchsorted(csum, pos, side='right') for the 16 positions ----
  if (tid < 16) {
    const int pos = rbase + tid;
    int src = -1;
    if (pos < total) {
      int lo = 0, hi = TT;
      while (lo < hi) {
        const int mid = (lo + hi) >> 1;
        if (csum[mid] <= pos) lo = mid + 1;
        else hi = mid;
      }
      src = lo;  // pos < total guarantees lo <= TT-1
    }
    s_src[tid] = src;
  }
  __syncthreads();

  // ---- 3. copy: wave wid owns rows rbase + wid*4 .. +3 ----
  int s[4];
#pragma unroll
  for (int i = 0; i < 4; ++i) s[i] = s_src[wid * 4 + i];

  const v4f* xb = x + (size_t)b * TT * (DD / 4);
  v4f a0[4], a1[4];
#pragma unroll
  for (int i = 0; i < 4; ++i) {  // issue all 8 loads before any store (MLP)
    const int src = (s[i] < 0) ? 0 : s[i];
    const v4f* ip = xb + (size_t)src * (DD / 4);
    a0[i] = ip[lane];
    a1[i] = ip[lane + 64];
  }
  const v4f z = {0.f, 0.f, 0.f, 0.f};
#pragma unroll
  for (int i = 0; i < 4; ++i) {
    if (s[i] < 0) { a0[i] = z; a1[i] = z; }
    v4f* op = out + (size_t)(b * MAXLEN + rbase + wid * 4 + i) * (DD / 4);
    __builtin_nontemporal_store(a0[i], op + lane);
    __builtin_nontemporal_store(a1[i], op + lane + 64);
  }
}

extern "C" void kernel_launch(void* const* d_in, const int* in_sizes, int n_in,
                              void* d_out, int out_size, void* d_ws,
                              size_t ws_size, hipStream_t stream) {
  const float* x = (const float*)d_in[0];
  const int* dur = (const int*)d_in[1];

  const int blocks = BB * (MAXLEN / 16);  // 4096
  lr_fused_kernel<<<blocks, 256, 0, stream>>>((const v4f*)x, dur,
                                              (v4f*)d_out);
}

// Round 5
// 161.941 us; speedup vs baseline: 1.0382x; 1.0217x over previous
//
#include <hip/hip_runtime.h>

// LengthRegulator: out[b,pos,:] = x[b, src(b,pos), :] masked by pos < total[b]
// B=16, T=1024, D=512, MAXLEN=4096 (fixed by setup_inputs()).
//
// Single fused kernel, 512-thread blocks (8 waves), 32 output rows per block:
//   1. cooperative clamp+scan of the batch's 1024 durations (2/thread local
//      sum + wave shuffle scan + 8-wave LDS combine) -> csum[1024] in LDS
//   2. 32 threads binary-search their block's 32 positions -> s_src[32]
//   3. wave-per-row copy: wave w owns rows rbase+4w..+3; lane i moves
//      float4 i and i+64 of each row (fully coalesced 16B/lane).
// Plain (cached) stores: harness fills prove they reach ~6.5 TB/s; the
// earlier nontemporal variant measured no better (and R1 plain-store run
// was the best). 32 rows/block halves scan redundancy vs 16 rows/block.

#define BB 16
#define TT 1024
#define DD 512
#define MAXLEN 4096

typedef float v4f __attribute__((ext_vector_type(4)));
typedef int v2i __attribute__((ext_vector_type(2)));

__global__ __launch_bounds__(512) void lr_fused_kernel(
    const v4f* __restrict__ x, const int* __restrict__ dur,
    v4f* __restrict__ out) {
  const int blk = blockIdx.x;          // 2048 blocks
  const int b = blk >> 7;              // 128 blocks per batch
  const int rbase = (blk & 127) << 5;  // first of this block's 32 rows
  const int tid = threadIdx.x;
  const int lane = tid & 63;
  const int wid = tid >> 6;            // 8 waves

  __shared__ int csum[TT];  // inclusive cumsum of clamped durations
  __shared__ int wsum[8];
  __shared__ int s_src[32];

  // ---- 1. scan ----
  const v2i dd = ((const v2i*)(dur + b * TT))[tid];  // 2 durations/thread
  const int d0 = max(dd.x, 0), d1 = max(dd.y, 0);
  const int l1 = d0 + d1;

  int v = l1;  // inclusive wave scan of per-thread pair sums
#pragma unroll
  for (int off = 1; off < 64; off <<= 1) {
    const int n = __shfl_up(v, off, 64);
    if (lane >= off) v += n;
  }
  if (lane == 63) wsum[wid] = v;
  __syncthreads();

  int add = 0, total = 0;
#pragma unroll
  for (int i = 0; i < 8; ++i) {
    const int w = wsum[i];
    add += (i < wid) ? w : 0;
    total += w;
  }
  const int excl = add + v - l1;  // exclusive prefix before this pair
  csum[2 * tid + 0] = excl + d0;
  csum[2 * tid + 1] = excl + l1;
  __syncthreads();

  // ---- 2. searchsorted(csum, pos, side='right') for the 32 positions ----
  if (tid < 32) {
    const int pos = rbase + tid;
    int src = -1;
    if (pos < total) {
      int lo = 0, hi = TT;
      while (lo < hi) {
        const int mid = (lo + hi) >> 1;
        if (csum[mid] <= pos) lo = mid + 1;
        else hi = mid;
      }
      src = lo;  // pos < total guarantees lo <= TT-1
    }
    s_src[tid] = src;
  }
  __syncthreads();

  // ---- 3. copy: wave wid owns rows rbase + wid*4 .. +3 ----
  int s[4];
#pragma unroll
  for (int i = 0; i < 4; ++i) s[i] = s_src[wid * 4 + i];

  const v4f* xb = x + (size_t)b * TT * (DD / 4);
  v4f a0[4], a1[4];
#pragma unroll
  for (int i = 0; i < 4; ++i) {  // issue all 8 loads before any store (MLP)
    const int src = (s[i] < 0) ? 0 : s[i];
    const v4f* ip = xb + (size_t)src * (DD / 4);
    a0[i] = ip[lane];
    a1[i] = ip[lane + 64];
  }
  const v4f z = {0.f, 0.f, 0.f, 0.f};
#pragma unroll
  for (int i = 0; i < 4; ++i) {
    if (s[i] < 0) { a0[i] = z; a1[i] = z; }
    v4f* op = out + (size_t)(b * MAXLEN + rbase + wid * 4 + i) * (DD / 4);
    op[lane] = a0[i];
    op[lane + 64] = a1[i];
  }
}

extern "C" void kernel_launch(void* const* d_in, const int* in_sizes, int n_in,
                              void* d_out, int out_size, void* d_ws,
                              size_t ws_size, hipStream_t stream) {
  const float* x = (const float*)d_in[0];
  const int* dur = (const int*)d_in[1];

  const int blocks = BB * (MAXLEN / 32);  // 2048
  lr_fused_kernel<<<blocks, 512, 0, stream>>>((const v4f*)x, dur,
                                              (v4f*)d_out);
}